// Round 1
// baseline (4665.736 us; speedup 1.0000x reference)
//
#include <hip/hip_runtime.h>
#include <math.h>

#define K 32
#define G 8
#define SIGMA_V 1.0f
#define NBLOCKS 512
#define TPB 256

// ws layout (floats): raw[G][K][K] @ 0 (8192), musum[G][K] @ 8192 (256), cnt[G] @ 8448 (8)
#define RAW_OFF 0
#define MUSUM_OFF 8192
#define CNT_OFF 8448
#define WS_FLOATS 8456

#define ACC_CASE(gc, Av, Bv) do{ \
  acc[gc][0] =fmaf(Av.x,Bv.x,acc[gc][0]);  acc[gc][1] =fmaf(Av.x,Bv.y,acc[gc][1]);  \
  acc[gc][2] =fmaf(Av.x,Bv.z,acc[gc][2]);  acc[gc][3] =fmaf(Av.x,Bv.w,acc[gc][3]);  \
  acc[gc][4] =fmaf(Av.y,Bv.x,acc[gc][4]);  acc[gc][5] =fmaf(Av.y,Bv.y,acc[gc][5]);  \
  acc[gc][6] =fmaf(Av.y,Bv.z,acc[gc][6]);  acc[gc][7] =fmaf(Av.y,Bv.w,acc[gc][7]);  \
  acc[gc][8] =fmaf(Av.z,Bv.x,acc[gc][8]);  acc[gc][9] =fmaf(Av.z,Bv.y,acc[gc][9]);  \
  acc[gc][10]=fmaf(Av.z,Bv.z,acc[gc][10]); acc[gc][11]=fmaf(Av.z,Bv.w,acc[gc][11]); \
  acc[gc][12]=fmaf(Av.w,Bv.x,acc[gc][12]); acc[gc][13]=fmaf(Av.w,Bv.y,acc[gc][13]); \
  acc[gc][14]=fmaf(Av.w,Bv.z,acc[gc][14]); acc[gc][15]=fmaf(Av.w,Bv.w,acc[gc][15]); \
  msum[gc][0]+=Av.x; msum[gc][1]+=Av.y; msum[gc][2]+=Av.z; msum[gc][3]+=Av.w;       \
  cnt[gc]+=1.0f; }while(0)

#define PROC(gv, Av, Bv) switch(gv){ \
  case 0: ACC_CASE(0,Av,Bv); break; case 1: ACC_CASE(1,Av,Bv); break; \
  case 2: ACC_CASE(2,Av,Bv); break; case 3: ACC_CASE(3,Av,Bv); break; \
  case 4: ACC_CASE(4,Av,Bv); break; case 5: ACC_CASE(5,Av,Bv); break; \
  case 6: ACC_CASE(6,Av,Bv); break; default: ACC_CASE(7,Av,Bv); break; }

__global__ __launch_bounds__(TPB, 2) void gmm_stats(const float* __restrict__ mu,
                                                    const int* __restrict__ lab,
                                                    float* __restrict__ ws, int B) {
  const int tid  = threadIdx.x;
  const int wave = tid >> 6;
  const int lane = tid & 63;
  const int a_blk = lane >> 3;   // 0..7 -> rows a_blk*4 .. +3
  const int b_blk = lane & 7;    // 0..7 -> cols b_blk*4 .. +3
  const int rpb = B / NBLOCKS;   // 2048
  const int rpw = rpb / 4;       // 512 (contiguous rows per wave)
  const long wbase = (long)blockIdx.x * rpb + (long)wave * rpw;

  float acc[G][16];
  float msum[G][4];
  float cnt[G];
  #pragma unroll
  for (int g = 0; g < G; ++g) {
    cnt[g] = 0.f;
    #pragma unroll
    for (int e = 0; e < 16; ++e) acc[g][e] = 0.f;
    #pragma unroll
    for (int e = 0; e < 4; ++e) msum[g][e] = 0.f;
  }

  const float4* __restrict__ mu4 = reinterpret_cast<const float4*>(mu);

  // software-pipelined: prologue loads rows (wbase, wbase+1)
  float4 A0 = mu4[wbase * 8 + a_blk];
  float4 B0 = mu4[wbase * 8 + b_blk];
  float4 A1 = mu4[wbase * 8 + 8 + a_blk];
  float4 B1 = mu4[wbase * 8 + 8 + b_blk];
  int2 gcur = *reinterpret_cast<const int2*>(lab + wbase);

  #pragma unroll 1
  for (int q = 0; q < rpw; q += 2) {
    const int qn = (q + 2 < rpw) ? (q + 2) : 0;   // clamp: last prefetch reloads row 0 (harmless)
    const long rn = wbase + qn;
    float4 nA0 = mu4[rn * 8 + a_blk];
    float4 nB0 = mu4[rn * 8 + b_blk];
    float4 nA1 = mu4[rn * 8 + 8 + a_blk];
    float4 nB1 = mu4[rn * 8 + 8 + b_blk];
    int2 gnxt = *reinterpret_cast<const int2*>(lab + rn);

    const int g0 = __builtin_amdgcn_readfirstlane(gcur.x);  // wave-uniform -> scalar branch
    PROC(g0, A0, B0);
    const int g1 = __builtin_amdgcn_readfirstlane(gcur.y);
    PROC(g1, A1, B1);

    A0 = nA0; B0 = nB0; A1 = nA1; B1 = nB1; gcur = gnxt;
  }

  // block-level reduction of the 4 waves' outer-product accumulators, then one atomic per entry
  __shared__ float red[4][K * K];  // 16 KB
  const int a_base = a_blk * 4, b_base = b_blk * 4;
  #pragma unroll
  for (int g = 0; g < G; ++g) {
    __syncthreads();
    #pragma unroll
    for (int ii = 0; ii < 4; ++ii)
      #pragma unroll
      for (int jj = 0; jj < 4; ++jj)
        red[wave][(a_base + ii) * K + b_base + jj] = acc[g][ii * 4 + jj];
    __syncthreads();
    for (int e = tid; e < K * K; e += TPB) {
      float s = red[0][e] + red[1][e] + red[2][e] + red[3][e];
      atomicAdd(&ws[RAW_OFF + g * K * K + e], s);
    }
  }
  // per-group mean sums: 8 lanes (b_blk==0) hold distinct a-blocks
  if (b_blk == 0) {
    #pragma unroll
    for (int g = 0; g < G; ++g) {
      atomicAdd(&ws[MUSUM_OFF + g * K + a_base + 0], msum[g][0]);
      atomicAdd(&ws[MUSUM_OFF + g * K + a_base + 1], msum[g][1]);
      atomicAdd(&ws[MUSUM_OFF + g * K + a_base + 2], msum[g][2]);
      atomicAdd(&ws[MUSUM_OFF + g * K + a_base + 3], msum[g][3]);
    }
  }
  if (lane == 0) {
    #pragma unroll
    for (int g = 0; g < G; ++g) atomicAdd(&ws[CNT_OFF + g], cnt[g]);
  }
}

// Finalize: build sigma_g, invert via register Gauss-Jordan (SPD, no pivoting), logdet from
// pivots, pairwise KL. One wave per group, all fp64 (latency-trivial, kills cancellation error).
__global__ __launch_bounds__(512, 1) void gmm_finalize(const float* __restrict__ ws,
                                                       float* __restrict__ out, int B) {
  __shared__ double sig[G][K][K];   // 64 KB
  __shared__ double inv[G][K][K];   // 64 KB
  __shared__ double mg[G][K];
  __shared__ double ldet[G];
  __shared__ double cshared[G];
  __shared__ double pairsum[G];
  const int tid = threadIdx.x;
  const int w = tid >> 6;     // group id == wave id, 0..7
  const int lane = tid & 63;

  if (tid < G) cshared[tid] = (double)ws[CNT_OFF + tid];
  __syncthreads();
  const double cg = cshared[w];
  const double cinv = 1.0 / cg;
  if (lane < K) mg[w][lane] = (double)ws[MUSUM_OFF + w * K + lane] * cinv;
  __syncthreads();
  for (int e = lane; e < K * K; e += 64) {
    const int a = e >> 5, b = e & 31;
    double s = (double)ws[RAW_OFF + w * K * K + e] * cinv - mg[w][a] * mg[w][b];
    if (a == b) s += (double)SIGMA_V;
    sig[w][a][b] = s;
  }
  __syncthreads();

  // Gauss-Jordan on [A | I]: lane c owns augmented column c (c<32: A, c>=32: identity->inverse)
  const int c = lane & 31;
  double col[K];
  #pragma unroll
  for (int i2 = 0; i2 < K; ++i2) {
    double sv = sig[w][i2][c];
    col[i2] = (lane < K) ? sv : ((i2 == c) ? 1.0 : 0.0);
  }
  double ld = 0.0;
  #pragma unroll
  for (int j2 = 0; j2 < K; ++j2) {
    double rowj = col[j2];
    double p = __shfl(rowj, j2);      // pivot A[j][j] (uniform)
    double pinv = 1.0 / p;
    ld += log(p);                     // det = product of pivots (SPD -> all positive)
    double scaled = rowj * pinv;
    #pragma unroll
    for (int i2 = 0; i2 < K; ++i2) {
      if (i2 == j2) continue;
      double bij = __shfl(col[i2], j2);           // A[i][j] from lane j (uniform per i)
      col[i2] = fma(-bij, scaled, col[i2]);
    }
    col[j2] = scaled;
  }
  if (lane >= K) {
    #pragma unroll
    for (int i2 = 0; i2 < K; ++i2) inv[w][i2][lane - K] = col[i2];
  }
  if (lane == 0) ldet[w] = ld;
  __syncthreads();

  // pairwise KL: wave w computes row i=w of the GxG pair matrix
  // tr(inv_j sig_i) + d^T inv_j d  ==  sum_ab inv_j[a][b] * (sig_i[a][b] + d_a d_b)  (both symmetric)
  double accp = 0.0;
  for (int jj = 0; jj < G; ++jj) {
    const bool ok = (w < G - 1) && (jj >= 1) && (w != jj);
    if (ok) {
      double t = 0.0;
      for (int e = lane; e < K * K; e += 64) {
        const int a = e >> 5, b = e & 31;
        const double da = mg[jj][a] - mg[w][a];   // d[i,j] = mu_j - mu_i
        const double db = mg[jj][b] - mg[w][b];
        t += inv[jj][a][b] * (sig[w][a][b] + da * db);
      }
      #pragma unroll
      for (int off = 32; off >= 1; off >>= 1) t += __shfl_xor(t, off);
      if (lane == 0) {
        const double kl = 0.5 * (t - (double)K + ldet[jj] - ldet[w]);
        accp += kl * cshared[w] * cshared[jj];
      }
    }
  }
  if (lane == 0) pairsum[w] = accp;
  __syncthreads();
  if (tid == 0) {
    double tot = 0.0;
    #pragma unroll
    for (int q = 0; q < G; ++q) tot += pairsum[q];
    const double Bf = (double)B;
    out[0] = (float)(tot / (Bf * Bf));
  }
}

extern "C" void kernel_launch(void* const* d_in, const int* in_sizes, int n_in,
                              void* d_out, int out_size, void* d_ws, size_t ws_size,
                              hipStream_t stream) {
  const float* mu = (const float*)d_in[0];
  const int* lab = (const int*)d_in[1];
  float* ws = (float*)d_ws;
  float* out = (float*)d_out;
  const int B = in_sizes[1];  // 1048576 labels

  hipMemsetAsync(d_ws, 0, WS_FLOATS * sizeof(float), stream);
  hipLaunchKernelGGL(gmm_stats, dim3(NBLOCKS), dim3(TPB), 0, stream, mu, lab, ws, B);
  hipLaunchKernelGGL(gmm_finalize, dim3(1), dim3(512), 0, stream, ws, out, B);
}

// Round 2
// 606.411 us; speedup vs baseline: 7.6940x; 7.6940x over previous
//
#include <hip/hip_runtime.h>
#include <math.h>

#define K 32
#define G 8
#define SIGMA_V 1.0f
#define NBLOCKS 1024
#define TPB 256

// ws layout (floats): raw[G][K][K] @ 0 (8192), musum[G][K] @ 8192 (256), cnt[G] @ 8448 (8)
#define RAW_OFF 0
#define MUSUM_OFF 8192
#define CNT_OFF 8448
#define WS_FLOATS 8456

// Each thread owns a 2x2 tile of the 32x32 outer product, for all 8 groups:
// acc[8][4] = 32 VGPRs (vs 128 in round 1, which spilled).
#define ACC_CASE(gc_, Av, Bv_) do{ \
  acc[gc_][0]=fmaf(Av.x,Bv_.x,acc[gc_][0]); \
  acc[gc_][1]=fmaf(Av.x,Bv_.y,acc[gc_][1]); \
  acc[gc_][2]=fmaf(Av.y,Bv_.x,acc[gc_][2]); \
  acc[gc_][3]=fmaf(Av.y,Bv_.y,acc[gc_][3]); \
  if (a_blk==0){ msum[gc_][0]+=Bv_.x; msum[gc_][1]+=Bv_.y; } }while(0)

#define PROC(gv, Av, Bv_) switch(gv){ \
  case 0: ACC_CASE(0,Av,Bv_); break; case 1: ACC_CASE(1,Av,Bv_); break; \
  case 2: ACC_CASE(2,Av,Bv_); break; case 3: ACC_CASE(3,Av,Bv_); break; \
  case 4: ACC_CASE(4,Av,Bv_); break; case 5: ACC_CASE(5,Av,Bv_); break; \
  case 6: ACC_CASE(6,Av,Bv_); break; default: ACC_CASE(7,Av,Bv_); break; }

__global__ __launch_bounds__(TPB, 4) void gmm_stats(const float* __restrict__ mu,
                                                    const int* __restrict__ lab,
                                                    float* __restrict__ ws, int B) {
  const int tid = threadIdx.x;
  const int a_blk = tid >> 4;    // 0..15 -> output rows 2*a_blk..+1 (wave w owns rows 8w..8w+7)
  const int b_blk = tid & 15;    // 0..15 -> output cols 2*b_blk..+1
  const int rpb = B / NBLOCKS;   // 1024 rows per block; all 4 waves co-process each row
  const long rbase = (long)blockIdx.x * rpb;

  float acc[G][4];
  float msum[G][2];
  #pragma unroll
  for (int g = 0; g < G; ++g) {
    acc[g][0]=acc[g][1]=acc[g][2]=acc[g][3]=0.f;
    msum[g][0]=msum[g][1]=0.f;
  }

  const float2* __restrict__ mu2 = reinterpret_cast<const float2*>(mu);

  // 4 rows per iteration, 1-deep software pipeline (8 rows of fragments in flight)
  float2 A[4], Bv[4], nA[4], nBv[4];
  #pragma unroll
  for (int k = 0; k < 4; ++k) {
    A[k]  = mu2[(rbase + k) * 16 + a_blk];
    Bv[k] = mu2[(rbase + k) * 16 + b_blk];
  }
  int4 gc = *reinterpret_cast<const int4*>(lab + rbase);

  #pragma unroll 1
  for (int q = 0; q < rpb; q += 4) {
    const long rn = rbase + ((q + 4 < rpb) ? (q + 4) : 0);  // last prefetch wraps (harmless)
    #pragma unroll
    for (int k = 0; k < 4; ++k) {
      nA[k]  = mu2[rn * 16 + k * 16 + a_blk];
      nBv[k] = mu2[rn * 16 + k * 16 + b_blk];
    }
    int4 gn = *reinterpret_cast<const int4*>(lab + rn);

    const int g0 = __builtin_amdgcn_readfirstlane(gc.x);  // wave-uniform -> scalar switch
    PROC(g0, A[0], Bv[0]);
    const int g1 = __builtin_amdgcn_readfirstlane(gc.y);
    PROC(g1, A[1], Bv[1]);
    const int g2 = __builtin_amdgcn_readfirstlane(gc.z);
    PROC(g2, A[2], Bv[2]);
    const int g3 = __builtin_amdgcn_readfirstlane(gc.w);
    PROC(g3, A[3], Bv[3]);

    #pragma unroll
    for (int k = 0; k < 4; ++k) { A[k] = nA[k]; Bv[k] = nBv[k]; }
    gc = gn;
  }

  // Block already holds each output entry exactly once -> direct atomics (1024 adds/address)
  const int arow = a_blk * 2, bcol = b_blk * 2;
  #pragma unroll
  for (int g = 0; g < G; ++g) {
    float* base = &ws[RAW_OFF + g * K * K];
    atomicAdd(base + (arow    ) * K + bcol    , acc[g][0]);
    atomicAdd(base + (arow    ) * K + bcol + 1, acc[g][1]);
    atomicAdd(base + (arow + 1) * K + bcol    , acc[g][2]);
    atomicAdd(base + (arow + 1) * K + bcol + 1, acc[g][3]);
  }
  if (a_blk == 0) {
    #pragma unroll
    for (int g = 0; g < G; ++g) {
      atomicAdd(&ws[MUSUM_OFF + g * K + bcol    ], msum[g][0]);
      atomicAdd(&ws[MUSUM_OFF + g * K + bcol + 1], msum[g][1]);
    }
  }
}

// Per-group counts: separate lightweight histogram (keeps regs/instr out of the hot loop)
__global__ __launch_bounds__(256, 4) void gmm_hist(const int* __restrict__ lab,
                                                   float* __restrict__ ws, int B) {
  const int idx0 = blockIdx.x * blockDim.x + threadIdx.x;
  const int stride = gridDim.x * blockDim.x;
  int c[G];
  #pragma unroll
  for (int g = 0; g < G; ++g) c[g] = 0;
  for (int i = idx0; i < B; i += stride) {
    const int v = lab[i];
    #pragma unroll
    for (int g = 0; g < G; ++g) c[g] += (v == g) ? 1 : 0;
  }
  const int lane = threadIdx.x & 63;
  #pragma unroll
  for (int g = 0; g < G; ++g) {
    int t = c[g];
    #pragma unroll
    for (int off = 32; off >= 1; off >>= 1) t += __shfl_xor(t, off);
    if (lane == 0) atomicAdd(&ws[CNT_OFF + g], (float)t);
  }
}

// Finalize: build sigma_g, invert via register Gauss-Jordan (SPD, no pivoting), logdet from
// pivots, pairwise KL. One wave per group, all fp64 (latency-trivial, kills cancellation error).
__global__ __launch_bounds__(512, 1) void gmm_finalize(const float* __restrict__ ws,
                                                       float* __restrict__ out, int B) {
  __shared__ double sig[G][K][K];   // 64 KB
  __shared__ double inv[G][K][K];   // 64 KB
  __shared__ double mg[G][K];
  __shared__ double ldet[G];
  __shared__ double cshared[G];
  __shared__ double pairsum[G];
  const int tid = threadIdx.x;
  const int w = tid >> 6;     // group id == wave id, 0..7
  const int lane = tid & 63;

  if (tid < G) cshared[tid] = (double)ws[CNT_OFF + tid];
  __syncthreads();
  const double cg = cshared[w];
  const double cinv = 1.0 / cg;
  if (lane < K) mg[w][lane] = (double)ws[MUSUM_OFF + w * K + lane] * cinv;
  __syncthreads();
  for (int e = lane; e < K * K; e += 64) {
    const int a = e >> 5, b = e & 31;
    double s = (double)ws[RAW_OFF + w * K * K + e] * cinv - mg[w][a] * mg[w][b];
    if (a == b) s += (double)SIGMA_V;
    sig[w][a][b] = s;
  }
  __syncthreads();

  // Gauss-Jordan on [A | I]: lane c owns augmented column c (c<32: A, c>=32: identity->inverse)
  const int c = lane & 31;
  double col[K];
  #pragma unroll
  for (int i2 = 0; i2 < K; ++i2) {
    double sv = sig[w][i2][c];
    col[i2] = (lane < K) ? sv : ((i2 == c) ? 1.0 : 0.0);
  }
  double ld = 0.0;
  #pragma unroll
  for (int j2 = 0; j2 < K; ++j2) {
    double rowj = col[j2];
    double p = __shfl(rowj, j2);      // pivot A[j][j] (uniform)
    double pinv = 1.0 / p;
    ld += log(p);                     // det = product of pivots (SPD -> all positive)
    double scaled = rowj * pinv;
    #pragma unroll
    for (int i2 = 0; i2 < K; ++i2) {
      if (i2 == j2) continue;
      double bij = __shfl(col[i2], j2);           // A[i][j] from lane j (uniform per i)
      col[i2] = fma(-bij, scaled, col[i2]);
    }
    col[j2] = scaled;
  }
  if (lane >= K) {
    #pragma unroll
    for (int i2 = 0; i2 < K; ++i2) inv[w][i2][lane - K] = col[i2];
  }
  if (lane == 0) ldet[w] = ld;
  __syncthreads();

  // pairwise KL: wave w computes row i=w of the GxG pair matrix
  // tr(inv_j sig_i) + d^T inv_j d  ==  sum_ab inv_j[a][b] * (sig_i[a][b] + d_a d_b)
  double accp = 0.0;
  for (int jj = 0; jj < G; ++jj) {
    const bool ok = (w < G - 1) && (jj >= 1) && (w != jj);
    if (ok) {
      double t = 0.0;
      for (int e = lane; e < K * K; e += 64) {
        const int a = e >> 5, b = e & 31;
        const double da = mg[jj][a] - mg[w][a];   // d[i,j] = mu_j - mu_i
        const double db = mg[jj][b] - mg[w][b];
        t += inv[jj][a][b] * (sig[w][a][b] + da * db);
      }
      #pragma unroll
      for (int off = 32; off >= 1; off >>= 1) t += __shfl_xor(t, off);
      if (lane == 0) {
        const double kl = 0.5 * (t - (double)K + ldet[jj] - ldet[w]);
        accp += kl * cshared[w] * cshared[jj];
      }
    }
  }
  if (lane == 0) pairsum[w] = accp;
  __syncthreads();
  if (tid == 0) {
    double tot = 0.0;
    #pragma unroll
    for (int q = 0; q < G; ++q) tot += pairsum[q];
    const double Bf = (double)B;
    out[0] = (float)(tot / (Bf * Bf));
  }
}

extern "C" void kernel_launch(void* const* d_in, const int* in_sizes, int n_in,
                              void* d_out, int out_size, void* d_ws, size_t ws_size,
                              hipStream_t stream) {
  const float* mu = (const float*)d_in[0];
  const int* lab = (const int*)d_in[1];
  float* ws = (float*)d_ws;
  float* out = (float*)d_out;
  const int B = in_sizes[1];  // 1048576 labels

  hipMemsetAsync(d_ws, 0, WS_FLOATS * sizeof(float), stream);
  hipLaunchKernelGGL(gmm_hist, dim3(128), dim3(256), 0, stream, lab, ws, B);
  hipLaunchKernelGGL(gmm_stats, dim3(NBLOCKS), dim3(TPB), 0, stream, mu, lab, ws, B);
  hipLaunchKernelGGL(gmm_finalize, dim3(1), dim3(512), 0, stream, ws, out, B);
}

// Round 5
// 372.220 us; speedup vs baseline: 12.5349x; 1.6292x over previous
//
#include <hip/hip_runtime.h>
#include <math.h>

#define K 32
#define G 8
#define SIGMA_V 1.0f
#define SEG 512          // rows per stats segment/block

// ws layout (int32 indices into a flat 4-byte array)
#define RAW_OFF   0        // float[G*K*K] = 8192
#define MUSUM_OFF 8192     // float[G*K]   = 256
#define CNT_OFF   8448     // float[G]
#define ICNT_OFF  8456     // int[G]
#define CUR_OFF   8464     // int[G]
#define DESC_OFF  8480     // int[3 * nstats]  (nstats <= B/SEG + G)
#define IDX_OFF   16384    // int[B + pad]
#define HDR_INTS  16384

// ---------------- histogram ----------------
__global__ __launch_bounds__(256, 8) void gmm_hist(const int* __restrict__ lab,
                                                   int* __restrict__ wsI, int B) {
  __shared__ int h[G];
  if (threadIdx.x < G) h[threadIdx.x] = 0;
  __syncthreads();
  int c[G];
  #pragma unroll
  for (int g = 0; g < G; ++g) c[g] = 0;
  const int nt = gridDim.x * blockDim.x;
  const int4* lab4 = reinterpret_cast<const int4*>(lab);
  for (int i = blockIdx.x * blockDim.x + threadIdx.x; i < B / 4; i += nt) {
    const int4 v = lab4[i];
    #pragma unroll
    for (int g = 0; g < G; ++g)
      c[g] += (v.x == g) + (v.y == g) + (v.z == g) + (v.w == g);
  }
  const int lane = threadIdx.x & 63;
  #pragma unroll
  for (int g = 0; g < G; ++g) {
    int t = c[g];
    #pragma unroll
    for (int off = 32; off >= 1; off >>= 1) t += __shfl_xor(t, off);
    if (lane == 0) atomicAdd(&h[g], t);
  }
  __syncthreads();
  if (threadIdx.x < G) atomicAdd(&wsI[ICNT_OFF + threadIdx.x], h[threadIdx.x]);
}

// ---------------- prep: offsets (padded to 4), cursors, float counts, descriptors ----------------
__global__ void gmm_prep(float* __restrict__ ws, int* __restrict__ wsI, int B, int nstats) {
  __shared__ int off[G + 1], segb[G + 1], scnt[G];
  const int tid = threadIdx.x;
  if (tid == 0) {
    int o = 0, sb = 0;
    for (int g = 0; g < G; ++g) {
      const int c = wsI[ICNT_OFF + g];
      scnt[g] = c;
      off[g] = o; segb[g] = sb;
      ws[CNT_OFF + g] = (float)c;
      wsI[CUR_OFF + g] = o;
      o = (o + c + 3) & ~3;              // pad each group start to int4 alignment
      sb += (c + SEG - 1) / SEG;
    }
    off[G] = o; segb[G] = sb;
  }
  __syncthreads();
  for (int s2 = tid; s2 < nstats; s2 += blockDim.x) {
    int g = 0;
    while (g < G && !(s2 >= segb[g] && s2 < segb[g + 1])) ++g;
    int st = 0, cn = 0, gg = 0;
    if (g < G) {
      const int k = s2 - segb[g];
      st = off[g] + k * SEG;
      const int rem = scnt[g] - k * SEG;
      cn = rem < SEG ? rem : SEG;
      gg = g;
    }
    wsI[DESC_OFF + 3 * s2]     = st;
    wsI[DESC_OFF + 3 * s2 + 1] = cn;
    wsI[DESC_OFF + 3 * s2 + 2] = gg;
  }
}

// ---------------- scatter: build group-sorted row-index array ----------------
__global__ __launch_bounds__(256, 8) void gmm_scatter(const int* __restrict__ lab,
                                                      int* __restrict__ wsI, int B) {
  __shared__ int lcnt[G], lbase[G], lpos[G];
  const int tid = threadIdx.x;
  const int base = blockIdx.x * 1024;      // 1024 labels per block
  if (tid < G) { lcnt[tid] = 0; lpos[tid] = 0; }
  __syncthreads();
  const int4 v = *reinterpret_cast<const int4*>(lab + base + tid * 4);
  atomicAdd(&lcnt[v.x], 1); atomicAdd(&lcnt[v.y], 1);
  atomicAdd(&lcnt[v.z], 1); atomicAdd(&lcnt[v.w], 1);
  __syncthreads();
  if (tid < G) lbase[tid] = atomicAdd(&wsI[CUR_OFF + tid], lcnt[tid]);
  __syncthreads();
  int p;
  p = atomicAdd(&lpos[v.x], 1); wsI[IDX_OFF + lbase[v.x] + p] = base + tid * 4;
  p = atomicAdd(&lpos[v.y], 1); wsI[IDX_OFF + lbase[v.y] + p] = base + tid * 4 + 1;
  p = atomicAdd(&lpos[v.z], 1); wsI[IDX_OFF + lbase[v.z] + p] = base + tid * 4 + 2;
  p = atomicAdd(&lpos[v.w], 1); wsI[IDX_OFF + lbase[v.w] + p] = base + tid * 4 + 3;
}

// ---------------- stats over sorted segments: branch-free, acc[4] ----------------
#define LOADROW(rr, Adst, Bdst) { \
  const float2* rp = mu2 + (size_t)(unsigned)(rr) * 16; \
  Adst = rp[a_blk]; Bdst = rp[b_blk]; }

#define ROWFMA(Av, Bv_) { \
  acc0 = fmaf(Av.x, Bv_.x, acc0); acc1 = fmaf(Av.x, Bv_.y, acc1); \
  acc2 = fmaf(Av.y, Bv_.x, acc2); acc3 = fmaf(Av.y, Bv_.y, acc3); \
  if (a_blk == 0) { ms0 += Bv_.x; ms1 += Bv_.y; } }

__global__ __launch_bounds__(256, 4) void gmm_stats_sorted(const float* __restrict__ mu,
                                                           const int* __restrict__ wsI,
                                                           float* __restrict__ ws) {
  const int* d = wsI + DESC_OFF + 3 * blockIdx.x;
  const int s = __builtin_amdgcn_readfirstlane(d[0]);
  const int n = __builtin_amdgcn_readfirstlane(d[1]);
  const int g = __builtin_amdgcn_readfirstlane(d[2]);
  if (n == 0) return;

  const int tid = threadIdx.x;
  const int a_blk = tid >> 4;   // 0..15 -> rows 2a..2a+1
  const int b_blk = tid & 15;   // 0..15 -> cols 2b..2b+1
  float acc0 = 0.f, acc1 = 0.f, acc2 = 0.f, acc3 = 0.f, ms0 = 0.f, ms1 = 0.f;
  const float2* __restrict__ mu2 = reinterpret_cast<const float2*>(mu);
  const int* idxp = wsI + IDX_OFF + s;   // s is a multiple of 4 (padded offsets)

  const int n4 = n & ~3;
  if (n4) {
    int4 iv = *reinterpret_cast<const int4*>(idxp);
    float2 A0, A1, A2, A3, B0, B1, B2, B3;
    {
      const int r0 = __builtin_amdgcn_readfirstlane(iv.x);
      const int r1 = __builtin_amdgcn_readfirstlane(iv.y);
      const int r2 = __builtin_amdgcn_readfirstlane(iv.z);
      const int r3 = __builtin_amdgcn_readfirstlane(iv.w);
      LOADROW(r0, A0, B0); LOADROW(r1, A1, B1);
      LOADROW(r2, A2, B2); LOADROW(r3, A3, B3);
    }
    #pragma unroll 1
    for (int q = 0; q < n4; q += 4) {
      const int qn = (q + 4 < n4) ? (q + 4) : 0;   // wrap prefetch (discarded)
      const int4 ivn = *reinterpret_cast<const int4*>(idxp + qn);
      float2 nA0, nA1, nA2, nA3, nB0, nB1, nB2, nB3;
      const int r0 = __builtin_amdgcn_readfirstlane(ivn.x);
      const int r1 = __builtin_amdgcn_readfirstlane(ivn.y);
      const int r2 = __builtin_amdgcn_readfirstlane(ivn.z);
      const int r3 = __builtin_amdgcn_readfirstlane(ivn.w);
      LOADROW(r0, nA0, nB0); LOADROW(r1, nA1, nB1);
      LOADROW(r2, nA2, nB2); LOADROW(r3, nA3, nB3);

      ROWFMA(A0, B0); ROWFMA(A1, B1); ROWFMA(A2, B2); ROWFMA(A3, B3);

      A0 = nA0; A1 = nA1; A2 = nA2; A3 = nA3;
      B0 = nB0; B1 = nB1; B2 = nB2; B3 = nB3;
    }
  }
  for (int q = n4; q < n; ++q) {   // tail (<=3 rows)
    const int rr = __builtin_amdgcn_readfirstlane(idxp[q]);
    float2 Av, Bv_; LOADROW(rr, Av, Bv_);
    ROWFMA(Av, Bv_);
  }

  float* base = ws + RAW_OFF + g * K * K;
  const int arow = a_blk * 2, bcol = b_blk * 2;
  atomicAdd(base + (arow    ) * K + bcol    , acc0);
  atomicAdd(base + (arow    ) * K + bcol + 1, acc1);
  atomicAdd(base + (arow + 1) * K + bcol    , acc2);
  atomicAdd(base + (arow + 1) * K + bcol + 1, acc3);
  if (a_blk == 0) {
    atomicAdd(ws + MUSUM_OFF + g * K + bcol    , ms0);
    atomicAdd(ws + MUSUM_OFF + g * K + bcol + 1, ms1);
  }
}

// ---------------- fallback stats (round-2 switch version) if ws too small ----------------
#define ACC_CASE(gc_, Av, Bv_) do{ \
  acc[gc_][0]=fmaf(Av.x,Bv_.x,acc[gc_][0]); acc[gc_][1]=fmaf(Av.x,Bv_.y,acc[gc_][1]); \
  acc[gc_][2]=fmaf(Av.y,Bv_.x,acc[gc_][2]); acc[gc_][3]=fmaf(Av.y,Bv_.y,acc[gc_][3]); \
  if (a_blk==0){ msum[gc_][0]+=Bv_.x; msum[gc_][1]+=Bv_.y; } }while(0)
#define PROC(gv, Av, Bv_) switch(gv){ \
  case 0: ACC_CASE(0,Av,Bv_); break; case 1: ACC_CASE(1,Av,Bv_); break; \
  case 2: ACC_CASE(2,Av,Bv_); break; case 3: ACC_CASE(3,Av,Bv_); break; \
  case 4: ACC_CASE(4,Av,Bv_); break; case 5: ACC_CASE(5,Av,Bv_); break; \
  case 6: ACC_CASE(6,Av,Bv_); break; default: ACC_CASE(7,Av,Bv_); break; }

__global__ __launch_bounds__(256, 4) void gmm_stats_fb(const float* __restrict__ mu,
                                                       const int* __restrict__ lab,
                                                       float* __restrict__ ws, int B) {
  const int tid = threadIdx.x;
  const int a_blk = tid >> 4, b_blk = tid & 15;
  const int rpb = B / 1024;
  const long rbase = (long)blockIdx.x * rpb;
  float acc[G][4]; float msum[G][2];
  #pragma unroll
  for (int g = 0; g < G; ++g) { acc[g][0]=acc[g][1]=acc[g][2]=acc[g][3]=0.f; msum[g][0]=msum[g][1]=0.f; }
  const float2* __restrict__ mu2 = reinterpret_cast<const float2*>(mu);
  for (int q = 0; q < rpb; ++q) {
    const long r = rbase + q;
    const float2 Av = mu2[r * 16 + a_blk];
    const float2 Bv_ = mu2[r * 16 + b_blk];
    const int g0 = __builtin_amdgcn_readfirstlane(lab[r]);
    PROC(g0, Av, Bv_);
  }
  const int arow = a_blk * 2, bcol = b_blk * 2;
  #pragma unroll
  for (int g = 0; g < G; ++g) {
    float* base = &ws[RAW_OFF + g * K * K];
    atomicAdd(base + (arow)*K + bcol, acc[g][0]);
    atomicAdd(base + (arow)*K + bcol + 1, acc[g][1]);
    atomicAdd(base + (arow+1)*K + bcol, acc[g][2]);
    atomicAdd(base + (arow+1)*K + bcol + 1, acc[g][3]);
  }
  if (a_blk == 0)
    #pragma unroll
    for (int g = 0; g < G; ++g) {
      atomicAdd(&ws[MUSUM_OFF + g*K + bcol], msum[g][0]);
      atomicAdd(&ws[MUSUM_OFF + g*K + bcol + 1], msum[g][1]);
    }
}

// ---------------- finalize (fp64, unchanged from validated round 2) ----------------
__global__ __launch_bounds__(512, 1) void gmm_finalize(const float* __restrict__ ws,
                                                       float* __restrict__ out, int B) {
  __shared__ double sig[G][K][K];
  __shared__ double inv[G][K][K];
  __shared__ double mg[G][K];
  __shared__ double ldet[G];
  __shared__ double cshared[G];
  __shared__ double pairsum[G];
  const int tid = threadIdx.x;
  const int w = tid >> 6;
  const int lane = tid & 63;

  if (tid < G) cshared[tid] = (double)ws[CNT_OFF + tid];
  __syncthreads();
  const double cinv = 1.0 / cshared[w];
  if (lane < K) mg[w][lane] = (double)ws[MUSUM_OFF + w * K + lane] * cinv;
  __syncthreads();
  for (int e = lane; e < K * K; e += 64) {
    const int a = e >> 5, b = e & 31;
    double s = (double)ws[RAW_OFF + w * K * K + e] * cinv - mg[w][a] * mg[w][b];
    if (a == b) s += (double)SIGMA_V;
    sig[w][a][b] = s;
  }
  __syncthreads();

  const int c = lane & 31;
  double col[K];
  #pragma unroll
  for (int i2 = 0; i2 < K; ++i2) {
    double sv = sig[w][i2][c];
    col[i2] = (lane < K) ? sv : ((i2 == c) ? 1.0 : 0.0);
  }
  double ld = 0.0;
  #pragma unroll
  for (int j2 = 0; j2 < K; ++j2) {
    double rowj = col[j2];
    double p = __shfl(rowj, j2);
    double pinv = 1.0 / p;
    ld += log(p);
    double scaled = rowj * pinv;
    #pragma unroll
    for (int i2 = 0; i2 < K; ++i2) {
      if (i2 == j2) continue;
      double bij = __shfl(col[i2], j2);
      col[i2] = fma(-bij, scaled, col[i2]);
    }
    col[j2] = scaled;
  }
  if (lane >= K) {
    #pragma unroll
    for (int i2 = 0; i2 < K; ++i2) inv[w][i2][lane - K] = col[i2];
  }
  if (lane == 0) ldet[w] = ld;
  __syncthreads();

  double accp = 0.0;
  for (int jj = 0; jj < G; ++jj) {
    const bool ok = (w < G - 1) && (jj >= 1) && (w != jj);
    if (ok) {
      double t = 0.0;
      for (int e = lane; e < K * K; e += 64) {
        const int a = e >> 5, b = e & 31;
        const double da = mg[jj][a] - mg[w][a];
        const double db = mg[jj][b] - mg[w][b];
        t += inv[jj][a][b] * (sig[w][a][b] + da * db);
      }
      #pragma unroll
      for (int off = 32; off >= 1; off >>= 1) t += __shfl_xor(t, off);
      if (lane == 0) accp += 0.5 * (t - (double)K + ldet[jj] - ldet[w]) * cshared[w] * cshared[jj];
    }
  }
  if (lane == 0) pairsum[w] = accp;
  __syncthreads();
  if (tid == 0) {
    double tot = 0.0;
    #pragma unroll
    for (int q = 0; q < G; ++q) tot += pairsum[q];
    const double Bf = (double)B;
    out[0] = (float)(tot / (Bf * Bf));
  }
}

extern "C" void kernel_launch(void* const* d_in, const int* in_sizes, int n_in,
                              void* d_out, int out_size, void* d_ws, size_t ws_size,
                              hipStream_t stream) {
  const float* mu = (const float*)d_in[0];
  const int* lab = (const int*)d_in[1];
  float* ws = (float*)d_ws;
  int* wsI = (int*)d_ws;
  float* out = (float*)d_out;
  const int B = in_sizes[1];

  hipMemsetAsync(d_ws, 0, (size_t)DESC_OFF * 4, stream);
  hipLaunchKernelGGL(gmm_hist, dim3(256), dim3(256), 0, stream, lab, wsI, B);

  const size_t need = (size_t)(HDR_INTS + B + 64) * 4;
  if (ws_size >= need) {
    const int nstats = (B + SEG - 1) / SEG + G;
    hipLaunchKernelGGL(gmm_prep, dim3(1), dim3(256), 0, stream, ws, wsI, B, nstats);
    hipLaunchKernelGGL(gmm_scatter, dim3(B / 1024), dim3(256), 0, stream, lab, wsI, B);
    hipLaunchKernelGGL(gmm_stats_sorted, dim3(nstats), dim3(256), 0, stream, mu, wsI, ws);
  } else {
    hipLaunchKernelGGL(gmm_prep, dim3(1), dim3(256), 0, stream, ws, wsI, B, 0);
    hipLaunchKernelGGL(gmm_stats_fb, dim3(1024), dim3(256), 0, stream, mu, lab, ws, B);
  }
  hipLaunchKernelGGL(gmm_finalize, dim3(1), dim3(512), 0, stream, ws, out, B);
}

// Round 6
// 200.026 us; speedup vs baseline: 23.3257x; 1.8609x over previous
//
#include <hip/hip_runtime.h>
#include <math.h>

#define K 32
#define G 8
#define SIGMA_V 1.0f
#define RF __builtin_amdgcn_readfirstlane

// ws layout (4-byte units)
#define RAW_OFF   0        // float[G*K*K] = 8192
#define MUSUM_OFF 8192     // float[G*K]   = 256
#define CNT_OFF   8448     // float[G]
#define ICNT_OFF  8456     // int[G]
#define CUR_OFF   8464     // int[G]
#define DESC_OFF  8480     // int[4 * nblk] (nblk <= B/1024 + G)
#define IDX_OFF   16384    // int[B + 16*G]
#define HDR_INTS  16384

// ---------------- histogram ----------------
__global__ __launch_bounds__(256, 8) void gmm_hist(const int* __restrict__ lab,
                                                   int* __restrict__ wsI, int B) {
  __shared__ int h[G];
  if (threadIdx.x < G) h[threadIdx.x] = 0;
  __syncthreads();
  int c[G];
  #pragma unroll
  for (int g = 0; g < G; ++g) c[g] = 0;
  const int nt = gridDim.x * blockDim.x;
  const int4* lab4 = reinterpret_cast<const int4*>(lab);
  for (int i = blockIdx.x * blockDim.x + threadIdx.x; i < B / 4; i += nt) {
    const int4 v = lab4[i];
    #pragma unroll
    for (int g = 0; g < G; ++g)
      c[g] += (v.x == g) + (v.y == g) + (v.z == g) + (v.w == g);
  }
  const int lane = threadIdx.x & 63;
  #pragma unroll
  for (int g = 0; g < G; ++g) {
    int t = c[g];
    #pragma unroll
    for (int off = 32; off >= 1; off >>= 1) t += __shfl_xor(t, off);
    if (lane == 0) atomicAdd(&h[g], t);
  }
  __syncthreads();
  if (threadIdx.x < G) atomicAdd(&wsI[ICNT_OFF + threadIdx.x], h[threadIdx.x]);
}

// ---------------- prep: 16-padded offsets, cursors, per-block descriptors ----------------
__global__ void gmm_prep(float* __restrict__ ws, int* __restrict__ wsI, int B, int nblk) {
  __shared__ int off[G], bb[G + 1], scnt[G];
  const int tid = threadIdx.x;
  if (tid == 0) {
    int o = 0, b = 0;
    for (int g = 0; g < G; ++g) {
      const int c = wsI[ICNT_OFF + g];
      scnt[g] = c; off[g] = o; bb[g] = b;
      ws[CNT_OFF + g] = (float)c;
      wsI[CUR_OFF + g] = o;
      o = (o + c + 15) & ~15;          // 16-int padding: every block start is 16-aligned
      b += (c + 1023) >> 10;           // 1024 rows per stats block
    }
    bb[G] = b;
  }
  __syncthreads();
  for (int t = tid; t < nblk; t += blockDim.x) {
    int st = 0, cn = 0, gg = 0;
    #pragma unroll
    for (int g = 0; g < G; ++g) {
      if (t >= bb[g] && t < bb[g + 1]) {
        const int k = t - bb[g];
        st = off[g] + (k << 10);
        const int rem = scnt[g] - (k << 10);
        cn = rem < 1024 ? rem : 1024;
        gg = g;
      }
    }
    wsI[DESC_OFF + 4 * t]     = st;
    wsI[DESC_OFF + 4 * t + 1] = cn;
    wsI[DESC_OFF + 4 * t + 2] = gg;
    wsI[DESC_OFF + 4 * t + 3] = 0;
  }
}

// ---------------- scatter: build group-sorted row-index array ----------------
__global__ __launch_bounds__(256, 8) void gmm_scatter(const int* __restrict__ lab,
                                                      int* __restrict__ wsI, int B) {
  __shared__ int lcnt[G], lbase[G], lpos[G];
  const int tid = threadIdx.x;
  const int base = blockIdx.x * 1024;
  if (tid < G) { lcnt[tid] = 0; lpos[tid] = 0; }
  __syncthreads();
  const int4 v = *reinterpret_cast<const int4*>(lab + base + tid * 4);
  atomicAdd(&lcnt[v.x], 1); atomicAdd(&lcnt[v.y], 1);
  atomicAdd(&lcnt[v.z], 1); atomicAdd(&lcnt[v.w], 1);
  __syncthreads();
  if (tid < G) lbase[tid] = atomicAdd(&wsI[CUR_OFF + tid], lcnt[tid]);
  __syncthreads();
  int p;
  p = atomicAdd(&lpos[v.x], 1); wsI[IDX_OFF + lbase[v.x] + p] = base + tid * 4;
  p = atomicAdd(&lpos[v.y], 1); wsI[IDX_OFF + lbase[v.y] + p] = base + tid * 4 + 1;
  p = atomicAdd(&lpos[v.z], 1); wsI[IDX_OFF + lbase[v.z] + p] = base + tid * 4 + 2;
  p = atomicAdd(&lpos[v.w], 1); wsI[IDX_OFF + lbase[v.w] + p] = base + tid * 4 + 3;
}

// ---------------- stats: 1 wave = 256 rows of ONE group; 4x4 tile/lane ----------------
#define OUTER(a, b) { \
  acc[0]=fmaf(a.x,b.x,acc[0]);   acc[1]=fmaf(a.x,b.y,acc[1]);   acc[2]=fmaf(a.x,b.z,acc[2]);   acc[3]=fmaf(a.x,b.w,acc[3]); \
  acc[4]=fmaf(a.y,b.x,acc[4]);   acc[5]=fmaf(a.y,b.y,acc[5]);   acc[6]=fmaf(a.y,b.z,acc[6]);   acc[7]=fmaf(a.y,b.w,acc[7]); \
  acc[8]=fmaf(a.z,b.x,acc[8]);   acc[9]=fmaf(a.z,b.y,acc[9]);   acc[10]=fmaf(a.z,b.z,acc[10]); acc[11]=fmaf(a.z,b.w,acc[11]); \
  acc[12]=fmaf(a.w,b.x,acc[12]); acc[13]=fmaf(a.w,b.y,acc[13]); acc[14]=fmaf(a.w,b.z,acc[14]); acc[15]=fmaf(a.w,b.w,acc[15]); \
  if (i8 == 0) { ms[0]+=b.x; ms[1]+=b.y; ms[2]+=b.z; ms[3]+=b.w; } }

__global__ __launch_bounds__(256, 4) void gmm_stats2(const float* __restrict__ mu,
                                                     const int* __restrict__ wsI,
                                                     float* __restrict__ ws) {
  const int bd  = blockIdx.x * 4;
  const int s   = RF(wsI[DESC_OFF + bd]);
  const int cnt = RF(wsI[DESC_OFF + bd + 1]);
  const int g   = RF(wsI[DESC_OFF + bd + 2]);
  if (cnt <= 0) return;                      // uniform, before any barrier

  const int tid = threadIdx.x, wave = tid >> 6, lane = tid & 63;
  const int i8 = lane >> 3, j8 = lane & 7;   // lane = 8x8 grid; thread tile = rows 4*i8.., cols 4*j8..
  float acc[16], ms[4];
  #pragma unroll
  for (int e = 0; e < 16; ++e) acc[e] = 0.f;
  ms[0] = ms[1] = ms[2] = ms[3] = 0.f;

  int wcnt = cnt - wave * 256;
  wcnt = wcnt < 0 ? 0 : (wcnt > 256 ? 256 : wcnt);
  const int* idxp = wsI + IDX_OFF + s + wave * 256;   // s 16-aligned, so idxp int4-aligned

  if (wcnt > 0) {
    const int n16 = wcnt & ~15;
    if (n16) {
      int4 iv[4];
      #pragma unroll
      for (int k = 0; k < 4; ++k) iv[k] = *reinterpret_cast<const int4*>(idxp + 4 * k);
      #pragma unroll 1
      for (int c0 = 0; c0 < n16; c0 += 16) {
        int sr[16];
        #pragma unroll
        for (int k = 0; k < 4; ++k) {        // ONE vmcnt drain per 16 rows
          sr[4*k+0] = RF(iv[k].x); sr[4*k+1] = RF(iv[k].y);
          sr[4*k+2] = RF(iv[k].z); sr[4*k+3] = RF(iv[k].w);
        }
        if (c0 + 16 < n16) {                 // issue next idx AFTER rf (never drained)
          #pragma unroll
          for (int k = 0; k < 4; ++k)
            iv[k] = *reinterpret_cast<const int4*>(idxp + c0 + 16 + 4 * k);
        }
        float4 A[4], Bv[4], nA[4], nB[4];
        #pragma unroll
        for (int k = 0; k < 4; ++k) {
          const float* rp = mu + (size_t)(unsigned)sr[k] * K;   // scalar base -> saddr load
          A[k]  = *reinterpret_cast<const float4*>(rp + i8 * 4);
          Bv[k] = *reinterpret_cast<const float4*>(rp + j8 * 4);
        }
        #pragma unroll
        for (int grp = 0; grp < 4; ++grp) {
          if (grp < 3) {
            #pragma unroll
            for (int k = 0; k < 4; ++k) {
              const float* rp = mu + (size_t)(unsigned)sr[(grp + 1) * 4 + k] * K;
              nA[k] = *reinterpret_cast<const float4*>(rp + i8 * 4);
              nB[k] = *reinterpret_cast<const float4*>(rp + j8 * 4);
            }
          }
          #pragma unroll
          for (int k = 0; k < 4; ++k) {
            const float4 a = A[k], b = Bv[k];
            OUTER(a, b);
          }
          #pragma unroll
          for (int k = 0; k < 4; ++k) { A[k] = nA[k]; Bv[k] = nB[k]; }
        }
      }
    }
    for (int q = n16; q < wcnt; ++q) {       // tail <= 15 rows
      const int r = RF(idxp[q]);
      const float* rp = mu + (size_t)(unsigned)r * K;
      const float4 a = *reinterpret_cast<const float4*>(rp + i8 * 4);
      const float4 b = *reinterpret_cast<const float4*>(rp + j8 * 4);
      OUTER(a, b);
    }
  }

  // cross-wave LDS reduce (all 4 waves same group), then 1056 atomics/block
  __shared__ float red[4][1056];
  #pragma unroll
  for (int e = 0; e < 16; ++e) red[wave][lane * 16 + e] = acc[e];
  if (i8 == 0) {
    #pragma unroll
    for (int e = 0; e < 4; ++e) red[wave][1024 + j8 * 4 + e] = ms[e];
  }
  __syncthreads();
  for (int t = tid; t < 1056; t += 256) {
    const float sm = red[0][t] + red[1][t] + red[2][t] + red[3][t];
    if (t < 1024) {
      const int ln = t >> 4, e = t & 15;
      const int row = 4 * (ln >> 3) + (e >> 2), col = 4 * (ln & 7) + (e & 3);
      atomicAdd(ws + RAW_OFF + g * K * K + row * K + col, sm);
    } else {
      atomicAdd(ws + MUSUM_OFF + g * K + (t - 1024), sm);
    }
  }
}

// ---------------- fallback stats (round-2 style) if ws too small ----------------
#define ACC_CASE(gc_, Av, Bv_) do{ \
  facc[gc_][0]=fmaf(Av.x,Bv_.x,facc[gc_][0]); facc[gc_][1]=fmaf(Av.x,Bv_.y,facc[gc_][1]); \
  facc[gc_][2]=fmaf(Av.y,Bv_.x,facc[gc_][2]); facc[gc_][3]=fmaf(Av.y,Bv_.y,facc[gc_][3]); \
  if (a_blk==0){ msum[gc_][0]+=Bv_.x; msum[gc_][1]+=Bv_.y; } }while(0)
#define PROC(gv, Av, Bv_) switch(gv){ \
  case 0: ACC_CASE(0,Av,Bv_); break; case 1: ACC_CASE(1,Av,Bv_); break; \
  case 2: ACC_CASE(2,Av,Bv_); break; case 3: ACC_CASE(3,Av,Bv_); break; \
  case 4: ACC_CASE(4,Av,Bv_); break; case 5: ACC_CASE(5,Av,Bv_); break; \
  case 6: ACC_CASE(6,Av,Bv_); break; default: ACC_CASE(7,Av,Bv_); break; }

__global__ __launch_bounds__(256, 4) void gmm_stats_fb(const float* __restrict__ mu,
                                                       const int* __restrict__ lab,
                                                       float* __restrict__ ws, int B) {
  const int tid = threadIdx.x;
  const int a_blk = tid >> 4, b_blk = tid & 15;
  const int rpb = B / 1024;
  const long rbase = (long)blockIdx.x * rpb;
  float facc[G][4]; float msum[G][2];
  #pragma unroll
  for (int g = 0; g < G; ++g) { facc[g][0]=facc[g][1]=facc[g][2]=facc[g][3]=0.f; msum[g][0]=msum[g][1]=0.f; }
  const float2* __restrict__ mu2 = reinterpret_cast<const float2*>(mu);
  for (int q = 0; q < rpb; ++q) {
    const long r = rbase + q;
    const float2 Av = mu2[r * 16 + a_blk];
    const float2 Bv_ = mu2[r * 16 + b_blk];
    const int g0 = RF(lab[r]);
    PROC(g0, Av, Bv_);
  }
  const int arow = a_blk * 2, bcol = b_blk * 2;
  #pragma unroll
  for (int g = 0; g < G; ++g) {
    float* base = &ws[RAW_OFF + g * K * K];
    atomicAdd(base + (arow)*K + bcol, facc[g][0]);
    atomicAdd(base + (arow)*K + bcol + 1, facc[g][1]);
    atomicAdd(base + (arow+1)*K + bcol, facc[g][2]);
    atomicAdd(base + (arow+1)*K + bcol + 1, facc[g][3]);
  }
  if (a_blk == 0)
    #pragma unroll
    for (int g = 0; g < G; ++g) {
      atomicAdd(&ws[MUSUM_OFF + g*K + bcol], msum[g][0]);
      atomicAdd(&ws[MUSUM_OFF + g*K + bcol + 1], msum[g][1]);
    }
}

// ---------------- finalize (fp64, validated in rounds 2/5) ----------------
__global__ __launch_bounds__(512, 1) void gmm_finalize(const float* __restrict__ ws,
                                                       float* __restrict__ out, int B) {
  __shared__ double sig[G][K][K];
  __shared__ double inv[G][K][K];
  __shared__ double mg[G][K];
  __shared__ double ldet[G];
  __shared__ double cshared[G];
  __shared__ double pairsum[G];
  const int tid = threadIdx.x;
  const int w = tid >> 6;
  const int lane = tid & 63;

  if (tid < G) cshared[tid] = (double)ws[CNT_OFF + tid];
  __syncthreads();
  const double cinv = 1.0 / cshared[w];
  if (lane < K) mg[w][lane] = (double)ws[MUSUM_OFF + w * K + lane] * cinv;
  __syncthreads();
  for (int e = lane; e < K * K; e += 64) {
    const int a = e >> 5, b = e & 31;
    double s = (double)ws[RAW_OFF + w * K * K + e] * cinv - mg[w][a] * mg[w][b];
    if (a == b) s += (double)SIGMA_V;
    sig[w][a][b] = s;
  }
  __syncthreads();

  const int c = lane & 31;
  double col[K];
  #pragma unroll
  for (int i2 = 0; i2 < K; ++i2) {
    double sv = sig[w][i2][c];
    col[i2] = (lane < K) ? sv : ((i2 == c) ? 1.0 : 0.0);
  }
  double ld = 0.0;
  #pragma unroll
  for (int j2 = 0; j2 < K; ++j2) {
    double rowj = col[j2];
    double p = __shfl(rowj, j2);
    double pinv = 1.0 / p;
    ld += log(p);
    double scaled = rowj * pinv;
    #pragma unroll
    for (int i2 = 0; i2 < K; ++i2) {
      if (i2 == j2) continue;
      double bij = __shfl(col[i2], j2);
      col[i2] = fma(-bij, scaled, col[i2]);
    }
    col[j2] = scaled;
  }
  if (lane >= K) {
    #pragma unroll
    for (int i2 = 0; i2 < K; ++i2) inv[w][i2][lane - K] = col[i2];
  }
  if (lane == 0) ldet[w] = ld;
  __syncthreads();

  double accp = 0.0;
  for (int jj = 0; jj < G; ++jj) {
    const bool ok = (w < G - 1) && (jj >= 1) && (w != jj);
    if (ok) {
      double t = 0.0;
      for (int e = lane; e < K * K; e += 64) {
        const int a = e >> 5, b = e & 31;
        const double da = mg[jj][a] - mg[w][a];
        const double db = mg[jj][b] - mg[w][b];
        t += inv[jj][a][b] * (sig[w][a][b] + da * db);
      }
      #pragma unroll
      for (int off = 32; off >= 1; off >>= 1) t += __shfl_xor(t, off);
      if (lane == 0) accp += 0.5 * (t - (double)K + ldet[jj] - ldet[w]) * cshared[w] * cshared[jj];
    }
  }
  if (lane == 0) pairsum[w] = accp;
  __syncthreads();
  if (tid == 0) {
    double tot = 0.0;
    #pragma unroll
    for (int q = 0; q < G; ++q) tot += pairsum[q];
    const double Bf = (double)B;
    out[0] = (float)(tot / (Bf * Bf));
  }
}

extern "C" void kernel_launch(void* const* d_in, const int* in_sizes, int n_in,
                              void* d_out, int out_size, void* d_ws, size_t ws_size,
                              hipStream_t stream) {
  const float* mu = (const float*)d_in[0];
  const int* lab = (const int*)d_in[1];
  float* ws = (float*)d_ws;
  int* wsI = (int*)d_ws;
  float* out = (float*)d_out;
  const int B = in_sizes[1];

  hipMemsetAsync(d_ws, 0, (size_t)DESC_OFF * 4, stream);
  hipLaunchKernelGGL(gmm_hist, dim3(256), dim3(256), 0, stream, lab, wsI, B);

  const size_t need = (size_t)(HDR_INTS + B + 16 * G + 32) * 4;
  if (ws_size >= need) {
    const int nblk = B / 1024 + G;
    hipLaunchKernelGGL(gmm_prep, dim3(1), dim3(256), 0, stream, ws, wsI, B, nblk);
    hipLaunchKernelGGL(gmm_scatter, dim3(B / 1024), dim3(256), 0, stream, lab, wsI, B);
    hipLaunchKernelGGL(gmm_stats2, dim3(nblk), dim3(256), 0, stream, mu, wsI, ws);
  } else {
    hipLaunchKernelGGL(gmm_prep, dim3(1), dim3(256), 0, stream, ws, wsI, B, 0);
    hipLaunchKernelGGL(gmm_stats_fb, dim3(1024), dim3(256), 0, stream, mu, lab, ws, B);
  }
  hipLaunchKernelGGL(gmm_finalize, dim3(1), dim3(512), 0, stream, ws, out, B);
}